// Round 5
// baseline (4962.105 us; speedup 1.0000x reference)
//
#include <hip/hip_runtime.h>

#define T_STEPS 256
#define HH      100
#define ROWS    8
#define NMV     500    // active matvec threads (100 j-cols x 5 k-slices)
#define BLK     512

// ws float layout:
//   [0      .. 120000)  P packed weights: flat = (((m*4 + c)*5 + i)*500 + t)*4 + kk
//                       = W_m[c*100 + j][s*20 + i*4 + kk]  with t = s*100 + j
//                       m: 0=W_hh1, 1=W_ih2, 2=W_hh2
//   [120000 ..120400)   b1s = b_ih1 + b_hh1
//   [120400 ..120800)   b2s = b_ih2 + b_hh2
//   [120800 ..121200)   wis = W_ih1[:,0]
//   [121200 ..121300)   wls = W_lin[0][:]
//   [121300]            blin
#define WS_TOTAL 121301

__global__ __launch_bounds__(512) void pack_kernel(
    const float* __restrict__ Whh1, const float* __restrict__ Wih2,
    const float* __restrict__ Whh2,
    const float* __restrict__ bih1, const float* __restrict__ bhh1,
    const float* __restrict__ bih2, const float* __restrict__ bhh2,
    const float* __restrict__ Wih1, const float* __restrict__ Wlin,
    const float* __restrict__ blin, float* __restrict__ ws) {
  int idx = blockIdx.x * BLK + threadIdx.x;
  if (idx < 120000) {
    int kk = idx & 3;
    int q  = idx >> 2;          // ((m*4+c)*5+i)*500 + t
    int t  = q % 500;
    int q2 = q / 500;           // (m*4+c)*5 + i
    int i  = q2 % 5;
    int q3 = q2 / 5;            // m*4 + c
    int c  = q3 & 3;
    int m  = q3 >> 2;
    int s  = t / 100;
    int j  = t - s * 100;
    int col = c * 100 + j;      // output row of W (0..399)
    int k   = s * 20 + i * 4 + kk;  // 0..99
    const float* W = (m == 0) ? Whh1 : (m == 1) ? Wih2 : Whh2;
    ws[idx] = W[col * HH + k];
  } else if (idx < 120400) {
    int j = idx - 120000; ws[idx] = bih1[j] + bhh1[j];
  } else if (idx < 120800) {
    int j = idx - 120400; ws[idx] = bih2[j] + bhh2[j];
  } else if (idx < 121200) {
    ws[idx] = Wih1[idx - 120800];
  } else if (idx < 121300) {
    ws[idx] = Wlin[idx - 121200];
  } else if (idx == 121300) {
    ws[idx] = blin[0];
  }
}

__device__ __forceinline__ float sigf(float v) {
  return 1.0f / (1.0f + __expf(-v));
}
__device__ __forceinline__ float tanh_fast(float v) {
  float t = __expf(2.0f * v);
  return 1.0f - 2.0f / (t + 1.0f);
}
__device__ __forceinline__ void fma4(const float4 w, const float4 h, float& a) {
  a = fmaf(w.x, h.x, fmaf(w.y, h.y, fmaf(w.z, h.z, fmaf(w.w, h.w, a))));
}

// (512, 1): 1 block/CU min -> 8 waves/block = 2 waves/SIMD -> 256-VGPR cap.
// R4's default heuristic capped at 128 and spilled the register-resident
// weights to scratch (FETCH_SIZE 2.67 GB). Grid is 1 block/CU, so higher
// block-occupancy is worthless — spend the registers.
__global__ __launch_bounds__(512, 1) void lstm_persist(
    const float* __restrict__ x, const float* __restrict__ ws,
    float* __restrict__ out, int T) {
  __shared__ float gbp[5][ROWS][400];
  __shared__ __align__(16) float h1[ROWS][HH];
  __shared__ __align__(16) float h2[ROWS][HH];
  __shared__ float b1s[400], b2s[400], wis[400], wls[HH], xs[ROWS];

  const int tid = threadIdx.x;
  const int r0  = blockIdx.x * ROWS;

  // ---- init ----
  if (tid < 400) {
    b1s[tid] = ws[120000 + tid];
    b2s[tid] = ws[120400 + tid];
    wis[tid] = ws[120800 + tid];
  }
  if (tid < HH) wls[tid] = ws[121200 + tid];
#pragma unroll
  for (int p = 0; p < 2; ++p) {
    int e = tid + 512 * p;
    if (e < ROWS * HH) { (&h1[0][0])[e] = 0.0f; (&h2[0][0])[e] = 0.0f; }
  }
  if (tid < ROWS) xs[tid] = x[(r0 + tid) * T];
  __syncthreads();

  const bool mv  = (tid < NMV);
  const int  s   = tid / 100;          // k-slice 0..4
  const int  j   = tid - s * 100;      // col base 0..99
  const int  s20 = s * 20;
  const float* wp = ws + tid * 4;

  // ---- P1 (W_hh1 slice) permanently register-resident: 20 float4 ----
  float4 p1w[4][5];
  if (mv) {
#pragma unroll
    for (int g = 0; g < 4; ++g)
#pragma unroll
      for (int i = 0; i < 5; ++i)
        p1w[g][i] = *(const float4*)(wp + (g * 5 + i) * 2000);
  }

  // act-phase element assignment: pass0 -> e=tid, pass1 -> e=tid+512
  const int e0r = tid / 100, e0n = tid - e0r * 100;
  const int e1  = tid + 512;
  const int e1r = e1 / 100, e1n = e1 - e1r * 100;
  const bool a1 = (e1 < ROWS * HH);
  float c1a = 0.f, c1b = 0.f, c2a = 0.f, c2b = 0.f;

  float4 buf[4][4];   // mv2 pipeline ring: [slot][gate]

#pragma unroll 1
  for (int t = 0; t < T; ++t) {
    // ============ layer-1 matvec: W_hh1 @ h1 (register weights) ============
    if (mv) {
      // prologue prefetch for mv2: chunks 0..3 (P2, i=0..3); delivery
      // overlaps the mv1 FMA below and is drained by the phase barrier.
#pragma unroll
      for (int c = 0; c < 4; ++c)
#pragma unroll
        for (int g = 0; g < 4; ++g)
          buf[c][g] = *(const float4*)(wp + (20 + g * 5 + c) * 2000);

      float acc[4][8];
#pragma unroll
      for (int c = 0; c < 4; ++c)
#pragma unroll
        for (int r = 0; r < 8; ++r) acc[c][r] = 0.0f;
#pragma unroll
      for (int i = 0; i < 5; ++i)
#pragma unroll
        for (int r = 0; r < 8; ++r) {
          float4 h = *(const float4*)&h1[r][s20 + i * 4];
          fma4(p1w[0][i], h, acc[0][r]);
          fma4(p1w[1][i], h, acc[1][r]);
          fma4(p1w[2][i], h, acc[2][r]);
          fma4(p1w[3][i], h, acc[3][r]);
        }
#pragma unroll
      for (int c = 0; c < 4; ++c)
#pragma unroll
        for (int r = 0; r < 8; ++r) gbp[s][r][c * 100 + j] = acc[c][r];
    }
    __syncthreads();

    // ============ layer-1 activations ============
    {
      {
        float xv = xs[e0r];
        float g[4];
#pragma unroll
        for (int gg = 0; gg < 4; ++gg) {
          int jj = e0n + 100 * gg;
          float v = gbp[0][e0r][jj] + gbp[1][e0r][jj] + gbp[2][e0r][jj] +
                    gbp[3][e0r][jj] + gbp[4][e0r][jj];
          g[gg] = v + b1s[jj] + wis[jj] * xv;
        }
        float iv = sigf(g[0]), fv = sigf(g[1]);
        float gv = tanh_fast(g[2]), ov = sigf(g[3]);
        c1a = fv * c1a + iv * gv;
        h1[e0r][e0n] = ov * tanh_fast(c1a);
      }
      if (a1) {
        float xv = xs[e1r];
        float g[4];
#pragma unroll
        for (int gg = 0; gg < 4; ++gg) {
          int jj = e1n + 100 * gg;
          float v = gbp[0][e1r][jj] + gbp[1][e1r][jj] + gbp[2][e1r][jj] +
                    gbp[3][e1r][jj] + gbp[4][e1r][jj];
          g[gg] = v + b1s[jj] + wis[jj] * xv;
        }
        float iv = sigf(g[0]), fv = sigf(g[1]);
        float gv = tanh_fast(g[2]), ov = sigf(g[3]);
        c1b = fv * c1b + iv * gv;
        h1[e1r][e1n] = ov * tanh_fast(c1b);
      }
    }
    __syncthreads();

    // ============ layer-2 matvec: W_ih2 @ h1 + W_hh2 @ h2 (pipelined) ======
    if (mv) {
      float acc[4][8];
#pragma unroll
      for (int c = 0; c < 4; ++c)
#pragma unroll
        for (int r = 0; r < 8; ++r) acc[c][r] = 0.0f;

      // 10 chunks: c 0..4 = P2 (x h1), c 5..9 = P3 (x h2); slot ring of 4.
#pragma unroll
      for (int c = 0; c < 10; ++c) {
        const int slot = c & 3;
        const int ii   = (c < 5) ? c : c - 5;
#pragma unroll
        for (int r = 0; r < 8; ++r) {
          float4 h = (c < 5) ? *(const float4*)&h1[r][s20 + ii * 4]
                             : *(const float4*)&h2[r][s20 + ii * 4];
          fma4(buf[slot][0], h, acc[0][r]);
          fma4(buf[slot][1], h, acc[1][r]);
          fma4(buf[slot][2], h, acc[2][r]);
          fma4(buf[slot][3], h, acc[3][r]);
        }
        if (c + 4 < 10) {
          const int c2 = c + 4;
          const int mb = (c2 < 5) ? 20 : 40;
          const int i2 = (c2 < 5) ? c2 : c2 - 5;
#pragma unroll
          for (int g = 0; g < 4; ++g)
            buf[c2 & 3][g] = *(const float4*)(wp + (mb + g * 5 + i2) * 2000);
        }
      }
#pragma unroll
      for (int c = 0; c < 4; ++c)
#pragma unroll
        for (int r = 0; r < 8; ++r) gbp[s][r][c * 100 + j] = acc[c][r];
    }
    __syncthreads();

    // ============ layer-2 activations + x prefetch ============
    {
      {
        float g[4];
#pragma unroll
        for (int gg = 0; gg < 4; ++gg) {
          int jj = e0n + 100 * gg;
          float v = gbp[0][e0r][jj] + gbp[1][e0r][jj] + gbp[2][e0r][jj] +
                    gbp[3][e0r][jj] + gbp[4][e0r][jj];
          g[gg] = v + b2s[jj];
        }
        float iv = sigf(g[0]), fv = sigf(g[1]);
        float gv = tanh_fast(g[2]), ov = sigf(g[3]);
        c2a = fv * c2a + iv * gv;
        h2[e0r][e0n] = ov * tanh_fast(c2a);
      }
      if (a1) {
        float g[4];
#pragma unroll
        for (int gg = 0; gg < 4; ++gg) {
          int jj = e1n + 100 * gg;
          float v = gbp[0][e1r][jj] + gbp[1][e1r][jj] + gbp[2][e1r][jj] +
                    gbp[3][e1r][jj] + gbp[4][e1r][jj];
          g[gg] = v + b2s[jj];
        }
        float iv = sigf(g[0]), fv = sigf(g[1]);
        float gv = tanh_fast(g[2]), ov = sigf(g[3]);
        c2b = fv * c2b + iv * gv;
        h2[e1r][e1n] = ov * tanh_fast(c2b);
      }
    }
    if (tid < ROWS && (t + 1) < T) xs[tid] = x[(r0 + tid) * T + t + 1];
    __syncthreads();
  }

  // ============ output: out[r] = h2[r]·wlin + blin ============
  {
    int row  = tid >> 6;   // 0..7 (8 waves)
    int lane = tid & 63;
    float p = h2[row][lane] * wls[lane];
    if (lane + 64 < HH) p += h2[row][lane + 64] * wls[lane + 64];
#pragma unroll
    for (int off = 32; off > 0; off >>= 1) p += __shfl_down(p, off, 64);
    if (lane == 0) out[r0 + row] = p + ws[121300];
  }
}

// ---------------- launcher ----------------
extern "C" void kernel_launch(void* const* d_in, const int* in_sizes, int n_in,
                              void* d_out, int out_size, void* d_ws, size_t ws_size,
                              hipStream_t stream) {
  const float* x    = (const float*)d_in[0];
  const float* Wih1 = (const float*)d_in[1];
  const float* Whh1 = (const float*)d_in[2];
  const float* bih1 = (const float*)d_in[3];
  const float* bhh1 = (const float*)d_in[4];
  const float* Wih2 = (const float*)d_in[5];
  const float* Whh2 = (const float*)d_in[6];
  const float* bih2 = (const float*)d_in[7];
  const float* bhh2 = (const float*)d_in[8];
  const float* Wlin = (const float*)d_in[9];
  const float* blin = (const float*)d_in[10];

  float* ws  = (float*)d_ws;
  float* out = (float*)d_out;

  const int B = in_sizes[0] / T_STEPS;   // 2048

  pack_kernel<<<(WS_TOTAL + BLK - 1) / BLK, BLK, 0, stream>>>(
      Whh1, Wih2, Whh2, bih1, bhh1, bih2, bhh2, Wih1, Wlin, blin, ws);

  lstm_persist<<<B / ROWS, BLK, 0, stream>>>(x, ws, out, T_STEPS);
}

// Round 6
// 3415.303 us; speedup vs baseline: 1.4529x; 1.4529x over previous
//
#include <hip/hip_runtime.h>
#include <stdint.h>

#define T_STEPS 256
#define HH      100
#define ROWS    8
#define NMV     500    // active matvec threads (100 j-cols x 5 k-slices)
#define BLK     512

// ws float layout (identical to R3 — proven):
//   [0      .. 120000)  P packed: flat = (((m*4 + c)*5 + i)*500 + t)*4 + kk
//                       = W_m[c*100 + j][s*20 + i*4 + kk], t = s*100 + j
//                       m: 0=W_hh1, 1=W_ih2, 2=W_hh2
//   [120000..120400) b1s   [120400..120800) b2s   [120800..121200) wis
//   [121200..121300) wls   [121300] blin
#define WS_TOTAL 121301

__global__ __launch_bounds__(512) void pack_kernel(
    const float* __restrict__ Whh1, const float* __restrict__ Wih2,
    const float* __restrict__ Whh2,
    const float* __restrict__ bih1, const float* __restrict__ bhh1,
    const float* __restrict__ bih2, const float* __restrict__ bhh2,
    const float* __restrict__ Wih1, const float* __restrict__ Wlin,
    const float* __restrict__ blin, float* __restrict__ ws) {
  int idx = blockIdx.x * BLK + threadIdx.x;
  if (idx < 120000) {
    int kk = idx & 3;
    int q  = idx >> 2;
    int t  = q % 500;
    int q2 = q / 500;
    int i  = q2 % 5;
    int q3 = q2 / 5;
    int c  = q3 & 3;
    int m  = q3 >> 2;
    int s  = t / 100;
    int j  = t - s * 100;
    int col = c * 100 + j;
    int k   = s * 20 + i * 4 + kk;
    const float* W = (m == 0) ? Whh1 : (m == 1) ? Wih2 : Whh2;
    ws[idx] = W[col * HH + k];
  } else if (idx < 120400) {
    int j = idx - 120000; ws[idx] = bih1[j] + bhh1[j];
  } else if (idx < 120800) {
    int j = idx - 120400; ws[idx] = bih2[j] + bhh2[j];
  } else if (idx < 121200) {
    ws[idx] = Wih1[idx - 120800];
  } else if (idx < 121300) {
    ws[idx] = Wlin[idx - 121200];
  } else if (idx == 121300) {
    ws[idx] = blin[0];
  }
}

__device__ __forceinline__ float sigf(float v) {
  return 1.0f / (1.0f + __expf(-v));
}
__device__ __forceinline__ float tanh_fast(float v) {
  float t = __expf(2.0f * v);
  return 1.0f - 2.0f / (t + 1.0f);
}
__device__ __forceinline__ void fma4(const float4 w, const float4 h, float& a) {
  a = fmaf(w.x, h.x, fmaf(w.y, h.y, fmaf(w.z, h.z, fmaf(w.w, h.w, a))));
}

// async global->LDS DMA, 16 B per lane; dest = wave-uniform base + lane*16.
typedef const __attribute__((address_space(1))) uint32_t gu32;
typedef __attribute__((address_space(3))) uint32_t lu32;
__device__ __forceinline__ void stage16(const float* g, float* s) {
  __builtin_amdgcn_global_load_lds((gu32*)g, (lu32*)s, 16, 0, 0);
}

// dynamic LDS float offsets
#define L_STG 0        // [3 slots][2 gates][2048]        = 12288
#define L_GBP 12288    // [5 slices][8 rows][400]         = 16000
#define L_H1  28288    // [8][100]
#define L_H2  29088
#define L_B1  29888
#define L_B2  30288
#define L_WI  30688
#define L_WL  31088
#define L_XS  31188
#define L_TOT 31200    // 124800 B < 160 KiB

// Weight chunk n (0..29 per step): m=n/10 (P1/P2/P3), i=(n%10)>>1 (k-subchunk),
// gp=(n&1)*2 (gate pair), slot=n%3. 30%3==0 -> same slot pattern every step.
// Ring of 3, staged 2 ahead: issue(n+2) ; s_waitcnt vmcnt(4) ; compute(n).
// __syncthreads() drains vmcnt -> per-phase counts reset (safe, conservative).

__global__ __launch_bounds__(512) void lstm_persist(
    const float* __restrict__ x, const float* __restrict__ ws,
    float* __restrict__ out, int T) {
  extern __shared__ float sm[];
  float* stg = sm + L_STG;
  float* gbp = sm + L_GBP;
  float* h1  = sm + L_H1;
  float* h2  = sm + L_H2;
  float* b1s = sm + L_B1;
  float* b2s = sm + L_B2;
  float* wis = sm + L_WI;
  float* wls = sm + L_WL;
  float* xs  = sm + L_XS;

  const int tid = threadIdx.x;
  const int r0  = blockIdx.x * ROWS;

  if (tid < 400) {
    b1s[tid] = ws[120000 + tid];
    b2s[tid] = ws[120400 + tid];
    wis[tid] = ws[120800 + tid];
  }
  if (tid < HH) wls[tid] = ws[121200 + tid];
  for (int e = tid; e < ROWS * HH; e += BLK) { h1[e] = 0.0f; h2[e] = 0.0f; }
  if (tid < ROWS) xs[tid] = x[(r0 + tid) * T];

  const bool mvt = (tid < NMV);
  const int  s   = tid / 100;
  const int  s20 = s * 20;
  const int  j   = tid - s * 100;
  const float* wp = ws + tid * 4;
  const int tid4 = tid * 4;
  const int wb4  = (tid & 448) * 4;   // wave-uniform lane-0 base (floats)

  // prologue: stage chunks 0,1 (P1 i=0, gate pairs 0/2); init barrier drains.
  if (mvt) {
    stage16(wp +  0 * 2000, stg + (0 * 2 + 0) * 2048 + wb4);
    stage16(wp +  5 * 2000, stg + (0 * 2 + 1) * 2048 + wb4);
    stage16(wp + 10 * 2000, stg + (1 * 2 + 0) * 2048 + wb4);
    stage16(wp + 15 * 2000, stg + (1 * 2 + 1) * 2048 + wb4);
  }
  __syncthreads();

  const int e0r = tid / 100, e0n = tid - e0r * 100;
  const int e1  = tid + 512;
  const int e1r = e1 / 100, e1n = e1 - e1r * 100;
  const bool a1 = (e1 < ROWS * HH);
  float c1a = 0.f, c1b = 0.f, c2a = 0.f, c2b = 0.f;

#pragma unroll 1
  for (int t = 0; t < T; ++t) {
    // ============ layer-1 matvec: chunks 0..9 (P1 x h1) ============
    {
      float acc[4][8];
#pragma unroll
      for (int c = 0; c < 4; ++c)
#pragma unroll
        for (int r = 0; r < 8; ++r) acc[c][r] = 0.0f;
#pragma unroll
      for (int n = 0; n < 10; ++n) {
        {  // issue chunk n+2 (2..11; 10,11 are P2 — weights are t-invariant)
          const int n2 = n + 2;
          const int m2 = n2 / 10, i2 = (n2 % 10) >> 1, gp2 = (n2 & 1) * 2;
          const int sl2 = n2 % 3;
          if (mvt) {
            stage16(wp + (m2 * 20 + (gp2 + 0) * 5 + i2) * 2000,
                    stg + (sl2 * 2 + 0) * 2048 + wb4);
            stage16(wp + (m2 * 20 + (gp2 + 1) * 5 + i2) * 2000,
                    stg + (sl2 * 2 + 1) * 2048 + wb4);
          }
        }
        asm volatile("s_waitcnt vmcnt(4)" ::: "memory");
        __builtin_amdgcn_sched_barrier(0);
        if (mvt) {
          const int i = n >> 1, gp = (n & 1) * 2, sl = n % 3;
          const float4 wa = *(const float4*)&stg[(sl * 2 + 0) * 2048 + tid4];
          const float4 wb = *(const float4*)&stg[(sl * 2 + 1) * 2048 + tid4];
          const int ho = s20 + i * 4;
#pragma unroll
          for (int r = 0; r < 8; ++r) {
            const float4 h = *(const float4*)&h1[r * HH + ho];
            fma4(wa, h, acc[gp][r]);
            fma4(wb, h, acc[gp + 1][r]);
          }
        }
      }
      if (mvt) {
#pragma unroll
        for (int c = 0; c < 4; ++c)
#pragma unroll
          for (int r = 0; r < 8; ++r)
            gbp[(s * 8 + r) * 400 + c * 100 + j] = acc[c][r];
      }
    }
    __syncthreads();

    // ============ layer-1 activations ============
    {
      {
        float xv = xs[e0r];
        float g[4];
#pragma unroll
        for (int gg = 0; gg < 4; ++gg) {
          int jj = e0n + 100 * gg;
          float v = gbp[(0 * 8 + e0r) * 400 + jj] + gbp[(1 * 8 + e0r) * 400 + jj] +
                    gbp[(2 * 8 + e0r) * 400 + jj] + gbp[(3 * 8 + e0r) * 400 + jj] +
                    gbp[(4 * 8 + e0r) * 400 + jj];
          g[gg] = v + b1s[jj] + wis[jj] * xv;
        }
        float iv = sigf(g[0]), fv = sigf(g[1]);
        float gv = tanh_fast(g[2]), ov = sigf(g[3]);
        c1a = fv * c1a + iv * gv;
        h1[e0r * HH + e0n] = ov * tanh_fast(c1a);
      }
      if (a1) {
        float xv = xs[e1r];
        float g[4];
#pragma unroll
        for (int gg = 0; gg < 4; ++gg) {
          int jj = e1n + 100 * gg;
          float v = gbp[(0 * 8 + e1r) * 400 + jj] + gbp[(1 * 8 + e1r) * 400 + jj] +
                    gbp[(2 * 8 + e1r) * 400 + jj] + gbp[(3 * 8 + e1r) * 400 + jj] +
                    gbp[(4 * 8 + e1r) * 400 + jj];
          g[gg] = v + b1s[jj] + wis[jj] * xv;
        }
        float iv = sigf(g[0]), fv = sigf(g[1]);
        float gv = tanh_fast(g[2]), ov = sigf(g[3]);
        c1b = fv * c1b + iv * gv;
        h1[e1r * HH + e1n] = ov * tanh_fast(c1b);
      }
    }
    __syncthreads();

    // ============ layer-2 matvec: chunks 10..29 (P2 x h1 + P3 x h2) ========
    {
      float acc[4][8];
#pragma unroll
      for (int c = 0; c < 4; ++c)
#pragma unroll
        for (int r = 0; r < 8; ++r) acc[c][r] = 0.0f;
#pragma unroll
      for (int n = 10; n < 30; ++n) {
        {  // issue chunk (n+2)%30; 28,29 stage next step's P1 chunks 0,1
          const int n2 = (n + 2) % 30;
          const int m2 = n2 / 10, i2 = (n2 % 10) >> 1, gp2 = (n2 & 1) * 2;
          const int sl2 = n2 % 3;
          if (mvt) {
            stage16(wp + (m2 * 20 + (gp2 + 0) * 5 + i2) * 2000,
                    stg + (sl2 * 2 + 0) * 2048 + wb4);
            stage16(wp + (m2 * 20 + (gp2 + 1) * 5 + i2) * 2000,
                    stg + (sl2 * 2 + 1) * 2048 + wb4);
          }
        }
        asm volatile("s_waitcnt vmcnt(4)" ::: "memory");
        __builtin_amdgcn_sched_barrier(0);
        if (mvt) {
          const int i = (n % 10) >> 1, gp = (n & 1) * 2, sl = n % 3;
          const float4 wa = *(const float4*)&stg[(sl * 2 + 0) * 2048 + tid4];
          const float4 wb = *(const float4*)&stg[(sl * 2 + 1) * 2048 + tid4];
          const int ho = s20 + i * 4;
          const float* hb = (n < 20) ? h1 : h2;
#pragma unroll
          for (int r = 0; r < 8; ++r) {
            const float4 h = *(const float4*)&hb[r * HH + ho];
            fma4(wa, h, acc[gp][r]);
            fma4(wb, h, acc[gp + 1][r]);
          }
        }
      }
      if (mvt) {
#pragma unroll
        for (int c = 0; c < 4; ++c)
#pragma unroll
          for (int r = 0; r < 8; ++r)
            gbp[(s * 8 + r) * 400 + c * 100 + j] = acc[c][r];
      }
    }
    __syncthreads();

    // ============ layer-2 activations + x prefetch ============
    {
      {
        float g[4];
#pragma unroll
        for (int gg = 0; gg < 4; ++gg) {
          int jj = e0n + 100 * gg;
          float v = gbp[(0 * 8 + e0r) * 400 + jj] + gbp[(1 * 8 + e0r) * 400 + jj] +
                    gbp[(2 * 8 + e0r) * 400 + jj] + gbp[(3 * 8 + e0r) * 400 + jj] +
                    gbp[(4 * 8 + e0r) * 400 + jj];
          g[gg] = v + b2s[jj];
        }
        float iv = sigf(g[0]), fv = sigf(g[1]);
        float gv = tanh_fast(g[2]), ov = sigf(g[3]);
        c2a = fv * c2a + iv * gv;
        h2[e0r * HH + e0n] = ov * tanh_fast(c2a);
      }
      if (a1) {
        float g[4];
#pragma unroll
        for (int gg = 0; gg < 4; ++gg) {
          int jj = e1n + 100 * gg;
          float v = gbp[(0 * 8 + e1r) * 400 + jj] + gbp[(1 * 8 + e1r) * 400 + jj] +
                    gbp[(2 * 8 + e1r) * 400 + jj] + gbp[(3 * 8 + e1r) * 400 + jj] +
                    gbp[(4 * 8 + e1r) * 400 + jj];
          g[gg] = v + b2s[jj];
        }
        float iv = sigf(g[0]), fv = sigf(g[1]);
        float gv = tanh_fast(g[2]), ov = sigf(g[3]);
        c2b = fv * c2b + iv * gv;
        h2[e1r * HH + e1n] = ov * tanh_fast(c2b);
      }
    }
    if (tid < ROWS && (t + 1) < T) xs[tid] = x[(r0 + tid) * T + t + 1];
    __syncthreads();
  }

  // ============ output: out[r] = h2[r]·wlin + blin ============
  {
    int row  = tid >> 6;
    int lane = tid & 63;
    float p = h2[row * HH + lane] * wls[lane];
    if (lane + 64 < HH) p += h2[row * HH + lane + 64] * wls[lane + 64];
#pragma unroll
    for (int off = 32; off > 0; off >>= 1) p += __shfl_down(p, off, 64);
    if (lane == 0) out[r0 + row] = p + ws[121300];
  }
}

// ---------------- launcher ----------------
extern "C" void kernel_launch(void* const* d_in, const int* in_sizes, int n_in,
                              void* d_out, int out_size, void* d_ws, size_t ws_size,
                              hipStream_t stream) {
  const float* x    = (const float*)d_in[0];
  const float* Wih1 = (const float*)d_in[1];
  const float* Whh1 = (const float*)d_in[2];
  const float* bih1 = (const float*)d_in[3];
  const float* bhh1 = (const float*)d_in[4];
  const float* Wih2 = (const float*)d_in[5];
  const float* Whh2 = (const float*)d_in[6];
  const float* bih2 = (const float*)d_in[7];
  const float* bhh2 = (const float*)d_in[8];
  const float* Wlin = (const float*)d_in[9];
  const float* blin = (const float*)d_in[10];

  float* ws  = (float*)d_ws;
  float* out = (float*)d_out;

  const int B = in_sizes[0] / T_STEPS;   // 2048

  pack_kernel<<<(WS_TOTAL + BLK - 1) / BLK, BLK, 0, stream>>>(
      Whh1, Wih2, Whh2, bih1, bhh1, bih2, bhh2, Wih1, Wlin, blin, ws);

  lstm_persist<<<B / ROWS, BLK, L_TOT * 4, stream>>>(x, ws, out, T_STEPS);
}

// Round 7
// 2984.433 us; speedup vs baseline: 1.6627x; 1.1444x over previous
//
#include <hip/hip_runtime.h>

#define T_STEPS 256
#define HH      100
#define ROWS    8
#define NMV     500    // active matvec threads (100 j-cols x 5 k-slices)
#define BLK     512

// ws float layout (identical to R3 — proven):
//   [0      .. 120000)  P packed: flat = (((m*4 + c)*5 + i)*500 + t)*4 + kk
//                       = W_m[c*100 + j][s*20 + i*4 + kk], t = s*100 + j
//                       m: 0=W_hh1, 1=W_ih2, 2=W_hh2
//   [120000..120400) b1s   [120400..120800) b2s   [120800..121200) wis
//   [121200..121300) wls   [121300] blin
#define WS_TOTAL 121301

__global__ __launch_bounds__(512) void pack_kernel(
    const float* __restrict__ Whh1, const float* __restrict__ Wih2,
    const float* __restrict__ Whh2,
    const float* __restrict__ bih1, const float* __restrict__ bhh1,
    const float* __restrict__ bih2, const float* __restrict__ bhh2,
    const float* __restrict__ Wih1, const float* __restrict__ Wlin,
    const float* __restrict__ blin, float* __restrict__ ws) {
  int idx = blockIdx.x * BLK + threadIdx.x;
  if (idx < 120000) {
    int kk = idx & 3;
    int q  = idx >> 2;
    int t  = q % 500;
    int q2 = q / 500;
    int i  = q2 % 5;
    int q3 = q2 / 5;
    int c  = q3 & 3;
    int m  = q3 >> 2;
    int s  = t / 100;
    int j  = t - s * 100;
    int col = c * 100 + j;
    int k   = s * 20 + i * 4 + kk;
    const float* W = (m == 0) ? Whh1 : (m == 1) ? Wih2 : Whh2;
    ws[idx] = W[col * HH + k];
  } else if (idx < 120400) {
    int j = idx - 120000; ws[idx] = bih1[j] + bhh1[j];
  } else if (idx < 120800) {
    int j = idx - 120400; ws[idx] = bih2[j] + bhh2[j];
  } else if (idx < 121200) {
    ws[idx] = Wih1[idx - 120800];
  } else if (idx < 121300) {
    ws[idx] = Wlin[idx - 121200];
  } else if (idx == 121300) {
    ws[idx] = blin[0];
  }
}

__device__ __forceinline__ float sigf(float v) {
  return 1.0f / (1.0f + __expf(-v));
}
__device__ __forceinline__ float tanh_fast(float v) {
  float t = __expf(2.0f * v);
  return 1.0f - 2.0f / (t + 1.0f);
}
__device__ __forceinline__ void fma4(const float4 w, const float4 h, float& a) {
  a = fmaf(w.x, h.x, fmaf(w.y, h.y, fmaf(w.z, h.z, fmaf(w.w, h.w, a))));
}

// Barrier with LDS-only drain: all cross-thread data flows through LDS
// (lgkmcnt); do NOT drain vmcnt — register weight-prefetch stays in flight.
#define BAR()                                                 \
  do {                                                        \
    asm volatile("s_waitcnt lgkmcnt(0)" ::: "memory");        \
    __builtin_amdgcn_s_barrier();                             \
  } while (0)

// weight float4 offset for (mat m, gate c, k-subchunk i) at this thread
#define CH_OFF(m, c, i) ((((m) * 4 + (c)) * 5 + (i)) * 2000)

// waves_per_eu(2): target 2 waves/SIMD (= our 1x512 block/CU) -> 256-VGPR
// budget, so the ring-of-5 weight prefetch (80 VGPRs) fits without spill.
__global__ __launch_bounds__(512) __attribute__((amdgpu_waves_per_eu(2)))
void lstm_persist(const float* __restrict__ x, const float* __restrict__ ws,
                  float* __restrict__ out, int T) {
  __shared__ float gbp[5][ROWS][400];
  __shared__ __align__(16) float h1[ROWS][HH];
  __shared__ __align__(16) float h2[ROWS][HH];
  __shared__ float b1s[400], b2s[400], wis[400], wls[HH], xs[ROWS];

  const int tid = threadIdx.x;
  const int r0  = blockIdx.x * ROWS;

  const bool mv  = (tid < NMV);
  const int  s   = tid / 100;          // k-slice 0..4
  const int  j   = tid - s * 100;      // col base 0..99
  const int  s20 = s * 20;
  const float* wp = ws + tid * 4;

  // ---- ring prologue: issue all of m=0 (P1) into buf; overlaps init ----
  float4 buf[5][4];
  if (mv) {
#pragma unroll
    for (int i = 0; i < 5; ++i)
#pragma unroll
      for (int c = 0; c < 4; ++c)
        buf[i][c] = *(const float4*)(wp + CH_OFF(0, c, i));
  }

  // ---- init ----
  if (tid < 400) {
    b1s[tid] = ws[120000 + tid];
    b2s[tid] = ws[120400 + tid];
    wis[tid] = ws[120800 + tid];
  }
  if (tid < HH) wls[tid] = ws[121200 + tid];
#pragma unroll
  for (int p = 0; p < 2; ++p) {
    int e = tid + 512 * p;
    if (e < ROWS * HH) { (&h1[0][0])[e] = 0.0f; (&h2[0][0])[e] = 0.0f; }
  }
  if (tid < ROWS) xs[tid] = x[(r0 + tid) * T];
  __syncthreads();

  const int e0r = tid / 100, e0n = tid - e0r * 100;
  const int e1  = tid + 512;
  const int e1r = e1 / 100, e1n = e1 - e1r * 100;
  const bool a1 = (e1 < ROWS * HH);
  float c1a = 0.f, c1b = 0.f, c2a = 0.f, c2b = 0.f;

#pragma unroll 1
  for (int t = 0; t < T; ++t) {
    // ============ layer-1 matvec: P1 x h1 (consume m=0, refill m=1) =======
    if (mv) {
      float acc[4][8];
#pragma unroll
      for (int c = 0; c < 4; ++c)
#pragma unroll
        for (int r = 0; r < 8; ++r) acc[c][r] = 0.0f;
#pragma unroll
      for (int i = 0; i < 5; ++i) {
#pragma unroll
        for (int r = 0; r < 8; ++r) {
          float4 h = *(const float4*)&h1[r][s20 + i * 4];
          fma4(buf[i][0], h, acc[0][r]);
          fma4(buf[i][1], h, acc[1][r]);
          fma4(buf[i][2], h, acc[2][r]);
          fma4(buf[i][3], h, acc[3][r]);
        }
#pragma unroll
        for (int c = 0; c < 4; ++c)
          buf[i][c] = *(const float4*)(wp + CH_OFF(1, c, i));
      }
#pragma unroll
      for (int c = 0; c < 4; ++c)
#pragma unroll
        for (int r = 0; r < 8; ++r) gbp[s][r][c * 100 + j] = acc[c][r];
    }
    BAR();

    // ============ layer-1 activations ============
    {
      {
        float xv = xs[e0r];
        float g[4];
#pragma unroll
        for (int gg = 0; gg < 4; ++gg) {
          int jj = e0n + 100 * gg;
          float v = gbp[0][e0r][jj] + gbp[1][e0r][jj] + gbp[2][e0r][jj] +
                    gbp[3][e0r][jj] + gbp[4][e0r][jj];
          g[gg] = v + b1s[jj] + wis[jj] * xv;
        }
        float iv = sigf(g[0]), fv = sigf(g[1]);
        float gv = tanh_fast(g[2]), ov = sigf(g[3]);
        c1a = fv * c1a + iv * gv;
        h1[e0r][e0n] = ov * tanh_fast(c1a);
      }
      if (a1) {
        float xv = xs[e1r];
        float g[4];
#pragma unroll
        for (int gg = 0; gg < 4; ++gg) {
          int jj = e1n + 100 * gg;
          float v = gbp[0][e1r][jj] + gbp[1][e1r][jj] + gbp[2][e1r][jj] +
                    gbp[3][e1r][jj] + gbp[4][e1r][jj];
          g[gg] = v + b1s[jj] + wis[jj] * xv;
        }
        float iv = sigf(g[0]), fv = sigf(g[1]);
        float gv = tanh_fast(g[2]), ov = sigf(g[3]);
        c1b = fv * c1b + iv * gv;
        h1[e1r][e1n] = ov * tanh_fast(c1b);
      }
    }
    BAR();

    // ============ layer-2 matvec: P2 x h1 + P3 x h2 ============
    if (mv) {
      float acc[4][8];
#pragma unroll
      for (int c = 0; c < 4; ++c)
#pragma unroll
        for (int r = 0; r < 8; ++r) acc[c][r] = 0.0f;
      // consume m=1 (x h1), refill m=2
#pragma unroll
      for (int i = 0; i < 5; ++i) {
#pragma unroll
        for (int r = 0; r < 8; ++r) {
          float4 h = *(const float4*)&h1[r][s20 + i * 4];
          fma4(buf[i][0], h, acc[0][r]);
          fma4(buf[i][1], h, acc[1][r]);
          fma4(buf[i][2], h, acc[2][r]);
          fma4(buf[i][3], h, acc[3][r]);
        }
#pragma unroll
        for (int c = 0; c < 4; ++c)
          buf[i][c] = *(const float4*)(wp + CH_OFF(2, c, i));
      }
      // consume m=2 (x h2), refill m=0 for NEXT step (weights t-invariant)
#pragma unroll
      for (int i = 0; i < 5; ++i) {
#pragma unroll
        for (int r = 0; r < 8; ++r) {
          float4 h = *(const float4*)&h2[r][s20 + i * 4];
          fma4(buf[i][0], h, acc[0][r]);
          fma4(buf[i][1], h, acc[1][r]);
          fma4(buf[i][2], h, acc[2][r]);
          fma4(buf[i][3], h, acc[3][r]);
        }
#pragma unroll
        for (int c = 0; c < 4; ++c)
          buf[i][c] = *(const float4*)(wp + CH_OFF(0, c, i));
      }
#pragma unroll
      for (int c = 0; c < 4; ++c)
#pragma unroll
        for (int r = 0; r < 8; ++r) gbp[s][r][c * 100 + j] = acc[c][r];
    }
    BAR();

    // ============ layer-2 activations + x prefetch ============
    {
      {
        float g[4];
#pragma unroll
        for (int gg = 0; gg < 4; ++gg) {
          int jj = e0n + 100 * gg;
          float v = gbp[0][e0r][jj] + gbp[1][e0r][jj] + gbp[2][e0r][jj] +
                    gbp[3][e0r][jj] + gbp[4][e0r][jj];
          g[gg] = v + b2s[jj];
        }
        float iv = sigf(g[0]), fv = sigf(g[1]);
        float gv = tanh_fast(g[2]), ov = sigf(g[3]);
        c2a = fv * c2a + iv * gv;
        h2[e0r][e0n] = ov * tanh_fast(c2a);
      }
      if (a1) {
        float g[4];
#pragma unroll
        for (int gg = 0; gg < 4; ++gg) {
          int jj = e1n + 100 * gg;
          float v = gbp[0][e1r][jj] + gbp[1][e1r][jj] + gbp[2][e1r][jj] +
                    gbp[3][e1r][jj] + gbp[4][e1r][jj];
          g[gg] = v + b2s[jj];
        }
        float iv = sigf(g[0]), fv = sigf(g[1]);
        float gv = tanh_fast(g[2]), ov = sigf(g[3]);
        c2b = fv * c2b + iv * gv;
        h2[e1r][e1n] = ov * tanh_fast(c2b);
      }
    }
    if (tid < ROWS && (t + 1) < T) xs[tid] = x[(r0 + tid) * T + t + 1];
    BAR();
  }

  // ============ output: out[r] = h2[r]·wlin + blin ============
  {
    int row  = tid >> 6;
    int lane = tid & 63;
    float p = h2[row][lane] * wls[lane];
    if (lane + 64 < HH) p += h2[row][lane + 64] * wls[lane + 64];
#pragma unroll
    for (int off = 32; off > 0; off >>= 1) p += __shfl_down(p, off, 64);
    if (lane == 0) out[r0 + row] = p + ws[121300];
  }
}

// ---------------- launcher ----------------
extern "C" void kernel_launch(void* const* d_in, const int* in_sizes, int n_in,
                              void* d_out, int out_size, void* d_ws, size_t ws_size,
                              hipStream_t stream) {
  const float* x    = (const float*)d_in[0];
  const float* Wih1 = (const float*)d_in[1];
  const float* Whh1 = (const float*)d_in[2];
  const float* bih1 = (const float*)d_in[3];
  const float* bhh1 = (const float*)d_in[4];
  const float* Wih2 = (const float*)d_in[5];
  const float* Whh2 = (const float*)d_in[6];
  const float* bih2 = (const float*)d_in[7];
  const float* bhh2 = (const float*)d_in[8];
  const float* Wlin = (const float*)d_in[9];
  const float* blin = (const float*)d_in[10];

  float* ws  = (float*)d_ws;
  float* out = (float*)d_out;

  const int B = in_sizes[0] / T_STEPS;   // 2048

  pack_kernel<<<(WS_TOTAL + BLK - 1) / BLK, BLK, 0, stream>>>(
      Whh1, Wih2, Whh2, bih1, bhh1, bih2, bhh2, Wih1, Wlin, blin, ws);

  lstm_persist<<<B / ROWS, BLK, 0, stream>>>(x, ws, out, T_STEPS);
}

// Round 8
// 2735.253 us; speedup vs baseline: 1.8141x; 1.0911x over previous
//
#include <hip/hip_runtime.h>

#define T_STEPS 256
#define HH      100
#define ROWS    8
#define NMV     500    // active matvec threads (100 j-cols x 5 k-slices)
#define BLK     512

// ws float layout (identical to R3 — proven):
//   [0      .. 120000)  P packed: flat = (((m*4 + c)*5 + i)*500 + t)*4 + kk
//                       = W_m[c*100 + j][s*20 + i*4 + kk], t = s*100 + j
//                       m: 0=W_hh1, 1=W_ih2, 2=W_hh2
//   [120000..120400) b1s   [120400..120800) b2s   [120800..121200) wis
//   [121200..121300) wls   [121300] blin
#define WS_TOTAL 121301

__global__ __launch_bounds__(512) void pack_kernel(
    const float* __restrict__ Whh1, const float* __restrict__ Wih2,
    const float* __restrict__ Whh2,
    const float* __restrict__ bih1, const float* __restrict__ bhh1,
    const float* __restrict__ bih2, const float* __restrict__ bhh2,
    const float* __restrict__ Wih1, const float* __restrict__ Wlin,
    const float* __restrict__ blin, float* __restrict__ ws) {
  int idx = blockIdx.x * BLK + threadIdx.x;
  if (idx < 120000) {
    int kk = idx & 3;
    int q  = idx >> 2;
    int t  = q % 500;
    int q2 = q / 500;
    int i  = q2 % 5;
    int q3 = q2 / 5;
    int c  = q3 & 3;
    int m  = q3 >> 2;
    int s  = t / 100;
    int j  = t - s * 100;
    int col = c * 100 + j;
    int k   = s * 20 + i * 4 + kk;
    const float* W = (m == 0) ? Whh1 : (m == 1) ? Wih2 : Whh2;
    ws[idx] = W[col * HH + k];
  } else if (idx < 120400) {
    int j = idx - 120000; ws[idx] = bih1[j] + bhh1[j];
  } else if (idx < 120800) {
    int j = idx - 120400; ws[idx] = bih2[j] + bhh2[j];
  } else if (idx < 121200) {
    ws[idx] = Wih1[idx - 120800];
  } else if (idx < 121300) {
    ws[idx] = Wlin[idx - 121200];
  } else if (idx == 121300) {
    ws[idx] = blin[0];
  }
}

__device__ __forceinline__ float sigf(float v) {
  return 1.0f / (1.0f + __expf(-v));
}
__device__ __forceinline__ float tanh_fast(float v) {
  float t = __expf(2.0f * v);
  return 1.0f - 2.0f / (t + 1.0f);
}
__device__ __forceinline__ void fma4(const float4 w, const float4 h, float& a) {
  a = fmaf(w.x, h.x, fmaf(w.y, h.y, fmaf(w.z, h.z, fmaf(w.w, h.w, a))));
}

// Barrier with LDS-only drain: all cross-thread data flows through LDS
// (lgkmcnt); do NOT drain vmcnt — register weight-prefetch stays in flight.
// (Proven correct in R7: absmax 0.0.)
#define BAR()                                                 \
  do {                                                        \
    asm volatile("s_waitcnt lgkmcnt(0)" ::: "memory");        \
    __builtin_amdgcn_s_barrier();                             \
  } while (0)

// weight float4 offset for (mat m, gate c, k-subchunk i) at this thread
#define CH_OFF(m, c, i) ((((m) * 4 + (c)) * 5 + (i)) * 2000)

// HARD CONSTRAINT (R4/R5/R7 evidence): this toolchain pins 512-thread
// kernels at 128 VGPRs; launch_bounds(,1) and amdgpu_waves_per_eu(2) do
// NOT raise it. Live set here: acc 32 + buf[3][4] 48 + ~25 temps ≈ 110.
__global__ __launch_bounds__(512) void lstm_persist(
    const float* __restrict__ x, const float* __restrict__ ws,
    float* __restrict__ out, int T) {
  __shared__ float gbp[5][ROWS][400];
  __shared__ __align__(16) float h1[ROWS][HH];
  __shared__ __align__(16) float h2[ROWS][HH];
  __shared__ float b1s[400], b2s[400], wis[400], wls[HH], xs[ROWS];

  const int tid = threadIdx.x;
  const int r0  = blockIdx.x * ROWS;

  const bool mv  = (tid < NMV);
  const int  s   = tid / 100;          // k-slice 0..4
  const int  j   = tid - s * 100;      // col base 0..99
  const int  s20 = s * 20;
  const float* wp = ws + tid * 4;

  // ---- ring-of-3 prologue: chunks 0,1,2 (m=0, i=0..2) -> slots 0,1,2 ----
  float4 buf[3][4];
  if (mv) {
#pragma unroll
    for (int n = 0; n < 3; ++n)
#pragma unroll
      for (int c = 0; c < 4; ++c)
        buf[n][c] = *(const float4*)(wp + CH_OFF(0, c, n));
  }

  // ---- init ----
  if (tid < 400) {
    b1s[tid] = ws[120000 + tid];
    b2s[tid] = ws[120400 + tid];
    wis[tid] = ws[120800 + tid];
  }
  if (tid < HH) wls[tid] = ws[121200 + tid];
#pragma unroll
  for (int p = 0; p < 2; ++p) {
    int e = tid + 512 * p;
    if (e < ROWS * HH) { (&h1[0][0])[e] = 0.0f; (&h2[0][0])[e] = 0.0f; }
  }
  if (tid < ROWS) xs[tid] = x[(r0 + tid) * T];
  __syncthreads();

  const int e0r = tid / 100, e0n = tid - e0r * 100;
  const int e1  = tid + 512;
  const int e1r = e1 / 100, e1n = e1 - e1r * 100;
  const bool a1 = (e1 < ROWS * HH);
  float c1a = 0.f, c1b = 0.f, c2a = 0.f, c2b = 0.f;

#pragma unroll 1
  for (int t = 0; t < T; ++t) {
    // ===== layer-1 matvec: chunks 0..4 (P1 x h1); refill n+3 =====
    if (mv) {
      float acc[4][8];
#pragma unroll
      for (int c = 0; c < 4; ++c)
#pragma unroll
        for (int r = 0; r < 8; ++r) acc[c][r] = 0.0f;
#pragma unroll
      for (int n = 0; n < 5; ++n) {
        const int sl = n % 3;
#pragma unroll
        for (int r = 0; r < 8; ++r) {
          float4 h = *(const float4*)&h1[r][s20 + n * 4];
          fma4(buf[sl][0], h, acc[0][r]);
          fma4(buf[sl][1], h, acc[1][r]);
          fma4(buf[sl][2], h, acc[2][r]);
          fma4(buf[sl][3], h, acc[3][r]);
        }
        const int nn = n + 3;            // 3..7: m = nn/5, i = nn%5
#pragma unroll
        for (int c = 0; c < 4; ++c)
          buf[sl][c] = *(const float4*)(wp + CH_OFF(nn / 5, c, nn % 5));
      }
#pragma unroll
      for (int c = 0; c < 4; ++c)
#pragma unroll
        for (int r = 0; r < 8; ++r) gbp[s][r][c * 100 + j] = acc[c][r];
    }
    BAR();

    // ===== layer-1 activations =====
    {
      {
        float xv = xs[e0r];
        float g[4];
#pragma unroll
        for (int gg = 0; gg < 4; ++gg) {
          int jj = e0n + 100 * gg;
          float v = gbp[0][e0r][jj] + gbp[1][e0r][jj] + gbp[2][e0r][jj] +
                    gbp[3][e0r][jj] + gbp[4][e0r][jj];
          g[gg] = v + b1s[jj] + wis[jj] * xv;
        }
        float iv = sigf(g[0]), fv = sigf(g[1]);
        float gv = tanh_fast(g[2]), ov = sigf(g[3]);
        c1a = fv * c1a + iv * gv;
        h1[e0r][e0n] = ov * tanh_fast(c1a);
      }
      if (a1) {
        float xv = xs[e1r];
        float g[4];
#pragma unroll
        for (int gg = 0; gg < 4; ++gg) {
          int jj = e1n + 100 * gg;
          float v = gbp[0][e1r][jj] + gbp[1][e1r][jj] + gbp[2][e1r][jj] +
                    gbp[3][e1r][jj] + gbp[4][e1r][jj];
          g[gg] = v + b1s[jj] + wis[jj] * xv;
        }
        float iv = sigf(g[0]), fv = sigf(g[1]);
        float gv = tanh_fast(g[2]), ov = sigf(g[3]);
        c1b = fv * c1b + iv * gv;
        h1[e1r][e1n] = ov * tanh_fast(c1b);
      }
    }
    BAR();

    // ===== layer-2 matvec: chunks 5..14 (P2 x h1, P3 x h2); refill (n+3)%15
    if (mv) {
      float acc[4][8];
#pragma unroll
      for (int c = 0; c < 4; ++c)
#pragma unroll
        for (int r = 0; r < 8; ++r) acc[c][r] = 0.0f;
#pragma unroll
      for (int n = 5; n < 15; ++n) {
        const int sl = n % 3;
        const int i  = n % 5;
#pragma unroll
        for (int r = 0; r < 8; ++r) {
          float4 h = (n < 10) ? *(const float4*)&h1[r][s20 + i * 4]
                              : *(const float4*)&h2[r][s20 + i * 4];
          fma4(buf[sl][0], h, acc[0][r]);
          fma4(buf[sl][1], h, acc[1][r]);
          fma4(buf[sl][2], h, acc[2][r]);
          fma4(buf[sl][3], h, acc[3][r]);
        }
        const int nn = (n + 3) % 15;     // 8..14, then 0,1,2 of next step
#pragma unroll
        for (int c = 0; c < 4; ++c)
          buf[sl][c] = *(const float4*)(wp + CH_OFF(nn / 5, c, nn % 5));
      }
#pragma unroll
      for (int c = 0; c < 4; ++c)
#pragma unroll
        for (int r = 0; r < 8; ++r) gbp[s][r][c * 100 + j] = acc[c][r];
    }
    BAR();

    // ===== layer-2 activations + x prefetch =====
    {
      {
        float g[4];
#pragma unroll
        for (int gg = 0; gg < 4; ++gg) {
          int jj = e0n + 100 * gg;
          float v = gbp[0][e0r][jj] + gbp[1][e0r][jj] + gbp[2][e0r][jj] +
                    gbp[3][e0r][jj] + gbp[4][e0r][jj];
          g[gg] = v + b2s[jj];
        }
        float iv = sigf(g[0]), fv = sigf(g[1]);
        float gv = tanh_fast(g[2]), ov = sigf(g[3]);
        c2a = fv * c2a + iv * gv;
        h2[e0r][e0n] = ov * tanh_fast(c2a);
      }
      if (a1) {
        float g[4];
#pragma unroll
        for (int gg = 0; gg < 4; ++gg) {
          int jj = e1n + 100 * gg;
          float v = gbp[0][e1r][jj] + gbp[1][e1r][jj] + gbp[2][e1r][jj] +
                    gbp[3][e1r][jj] + gbp[4][e1r][jj];
          g[gg] = v + b2s[jj];
        }
        float iv = sigf(g[0]), fv = sigf(g[1]);
        float gv = tanh_fast(g[2]), ov = sigf(g[3]);
        c2b = fv * c2b + iv * gv;
        h2[e1r][e1n] = ov * tanh_fast(c2b);
      }
    }
    if (tid < ROWS && (t + 1) < T) xs[tid] = x[(r0 + tid) * T + t + 1];
    BAR();
  }

  // ===== output: out[r] = h2[r]·wlin + blin =====
  {
    int row  = tid >> 6;
    int lane = tid & 63;
    float p = h2[row][lane] * wls[lane];
    if (lane + 64 < HH) p += h2[row][lane + 64] * wls[lane + 64];
#pragma unroll
    for (int off = 32; off > 0; off >>= 1) p += __shfl_down(p, off, 64);
    if (lane == 0) out[r0 + row] = p + ws[121300];
  }
}

// ---------------- launcher ----------------
extern "C" void kernel_launch(void* const* d_in, const int* in_sizes, int n_in,
                              void* d_out, int out_size, void* d_ws, size_t ws_size,
                              hipStream_t stream) {
  const float* x    = (const float*)d_in[0];
  const float* Wih1 = (const float*)d_in[1];
  const float* Whh1 = (const float*)d_in[2];
  const float* bih1 = (const float*)d_in[3];
  const float* bhh1 = (const float*)d_in[4];
  const float* Wih2 = (const float*)d_in[5];
  const float* Whh2 = (const float*)d_in[6];
  const float* bih2 = (const float*)d_in[7];
  const float* bhh2 = (const float*)d_in[8];
  const float* Wlin = (const float*)d_in[9];
  const float* blin = (const float*)d_in[10];

  float* ws  = (float*)d_ws;
  float* out = (float*)d_out;

  const int B = in_sizes[0] / T_STEPS;   // 2048

  pack_kernel<<<(WS_TOTAL + BLK - 1) / BLK, BLK, 0, stream>>>(
      Whh1, Wih2, Whh2, bih1, bhh1, bih2, bhh2, Wih1, Wlin, blin, ws);

  lstm_persist<<<B / ROWS, BLK, 0, stream>>>(x, ws, out, T_STEPS);
}